// Round 6
// baseline (112.752 us; speedup 1.0000x reference)
//
#include <hip/hip_runtime.h>
#include <math.h>

#define BATCH 8
#define TLEN 2000
#define DIM 512
#define MLEN (TLEN + 1)
#define NTH 1024             // scan block size
#define NWORD 32             // fire bitmask words (2000 bits)
#define MAXLVL 11
#define FPB 16               // frames per gather block
#define CPB ((MLEN + FPB - 1) / FPB)   // 126 chunks per batch

// K1: weight[b,t] = sigmoid(dot(feat[b,t,:], W) + bias). One wave per row.
__global__ __launch_bounds__(256) void weight_kernel(
    const float* __restrict__ feat, const float* __restrict__ W,
    const float* __restrict__ bias, float* __restrict__ weight) {
  int gwave = (blockIdx.x * 256 + threadIdx.x) >> 6;   // global wave id = row
  int lane  = threadIdx.x & 63;
  if (gwave >= BATCH * TLEN) return;
  const float4* f4 = (const float4*)feat + (size_t)gwave * (DIM / 4) + lane * 2;
  const float4* w4 = (const float4*)W + lane * 2;
  float4 a0 = f4[0], a1 = f4[1];
  float4 b0 = w4[0], b1 = w4[1];
  float s = a0.x * b0.x + a0.y * b0.y + a0.z * b0.z + a0.w * b0.w +
            a1.x * b1.x + a1.y * b1.y + a1.z * b1.z + a1.w * b1.w;
#pragma unroll
  for (int off = 32; off > 0; off >>= 1) s += __shfl_xor(s, off, 64);
  if (lane == 0) {
    float x = s + bias[0];
    weight[gwave] = 1.0f / (1.0f + expf(-x));
  }
}

// K2: fully parallel integrate-and-fire. Prefix sum (wave shuffles) ->
// next-fire table G0 (batched binary search) -> orbit via binary lifting
// with fused F-extension and early exit -> fire bitmask -> c0/c1 and
// packed per-frame ranges AB.
__global__ __launch_bounds__(NTH) void scan_kernel(
    const float* __restrict__ weight, float* __restrict__ hlens_out,
    float2* __restrict__ c01G, int2* __restrict__ AB) {
  int b = blockIdx.x;
  int tid = threadIdx.x;
  int lane = tid & 63, wid = tid >> 6;

  __shared__ float w_s[TLEN];
  __shared__ float S_s[TLEN];
  __shared__ float wtot[16];
  __shared__ unsigned short Ga_s[MLEN];    // ping
  __shared__ unsigned short Gb_s[MLEN];    // pong
  __shared__ unsigned short F_s[2048];     // fire positions (K <= 1000)
  __shared__ unsigned long long mask_s[NWORD];
  __shared__ int lastw_s[NWORD];           // last fire index < 64*w (or -1)
  __shared__ int done_lv[MAXLVL];
  __shared__ int K_s;

  // --- Phase 1: load + prefix sum via wave shuffles (2 elems/thread) ---
  const float* wrow = weight + b * TLEN;
  int base = tid * 2;
  float w0 = 0.f, w1 = 0.f;
  if (base < TLEN) {
    float2 v = *(const float2*)(wrow + base);
    w0 = v.x; w1 = v.y;
  }
  float mysum = w0 + w1;
  float sc = mysum;
#pragma unroll
  for (int d = 1; d < 64; d <<= 1) {
    float o = __shfl_up(sc, d, 64);
    if (lane >= d) sc += o;
  }
  if (lane == 63) wtot[wid] = sc;
  if (tid < NWORD) mask_s[tid] = 0ull;
  if (tid < MAXLVL) done_lv[tid] = 1;
  __syncthreads();
  float woff = 0.f;
  for (int j = 0; j < wid; j++) woff += wtot[j];
  float excl = woff + (sc - mysum);
  if (base < TLEN) {
    w_s[base] = w0; w_s[base + 1] = w1;
    S_s[base] = excl + w0;
    S_s[base + 1] = excl + w0 + w1;
  }
  if (tid == 0) {
    float tot = 0.f;
    for (int j = 0; j < 16; j++) tot += wtot[j];
    hlens_out[b] = ceilf(tot);              // hlens tol ~20: order irrelevant
  }
  __syncthreads();

  // --- Phase 2: G0[s] = min t>s with S[t] > S[s]+1; t0 = min t, S[t] > 1 ---
  {
    int l0 = tid + 1, r0 = TLEN;  float tg0 = S_s[tid] + 1.0f;
    int s1v = tid + 1024;
    bool has1 = (s1v < TLEN);
    int l1 = has1 ? s1v + 1 : TLEN, r1 = TLEN;
    float tg1 = has1 ? S_s[s1v] + 1.0f : 0.f;
    bool has2 = (tid == 0);
    int l2 = 0, r2 = has2 ? TLEN : 0;
#pragma unroll
    for (int step = 0; step < MAXLVL; step++) {
      if (l0 < r0) { int m = (l0 + r0) >> 1; if (S_s[m] > tg0) r0 = m; else l0 = m + 1; }
      if (l1 < r1) { int m = (l1 + r1) >> 1; if (S_s[m] > tg1) r1 = m; else l1 = m + 1; }
      if (l2 < r2) { int m = (l2 + r2) >> 1; if (S_s[m] > 1.0f) r2 = m; else l2 = m + 1; }
    }
    Ga_s[tid] = (unsigned short)l0;
    if (has1) Ga_s[s1v] = (unsigned short)l1;
    F_s[tid] = (unsigned short)TLEN;
    F_s[tid + 1024] = (unsigned short)TLEN;
    if (tid == 0) {
      Ga_s[TLEN] = (unsigned short)TLEN;    // sentinel self-loop
      F_s[0] = (unsigned short)l2;          // first fire (TLEN if none)
    }
  }
  __syncthreads();

  // --- Phase 3: lifting + fused orbit doubling, 1 barrier/level ---
  {
    unsigned short* cur = Ga_s;
    unsigned short* nxt = Gb_s;
    int flen = 1;
    for (int lvl = 0; lvl < MAXLVL; lvl++) {
      int s0 = tid, s1v = tid + 1024;
      int g20 = (int)cur[cur[s0]];
      int g21 = (s1v <= TLEN) ? (int)cur[cur[s1v]] : TLEN;
      int i0 = tid, i1 = tid + 1024;
      int nv0 = -1, nv1 = -1;
      if (i0 < flen) nv0 = (int)cur[F_s[i0]];
      if (i1 < flen) nv1 = (int)cur[F_s[i1]];
      nxt[s0] = (unsigned short)g20;
      if (s1v <= TLEN) nxt[s1v] = (unsigned short)g21;
      if (i0 < flen) { F_s[flen + i0] = (unsigned short)nv0; if (nv0 < TLEN) done_lv[lvl] = 0; }
      if (i1 < flen) { F_s[flen + i1] = (unsigned short)nv1; if (nv1 < TLEN) done_lv[lvl] = 0; }
      __syncthreads();
      flen <<= 1;
      unsigned short* t = cur; cur = nxt; nxt = t;
      if (done_lv[lvl]) break;
    }
  }

  // --- Phase 4: fire bitmask scatter ---
  {
    int t0v = (int)F_s[tid];
    int t1v = (int)F_s[tid + 1024];
    if (t0v < TLEN) atomicOr(&mask_s[t0v >> 6], 1ull << (t0v & 63));
    if (t1v < TLEN) atomicOr(&mask_s[t1v >> 6], 1ull << (t1v & 63));
  }
  __syncthreads();
  if (tid == 0) {
    int last = -1, cnt = 0;
    for (int wd = 0; wd < NWORD; wd++) {
      lastw_s[wd] = last;
      unsigned long long m = mask_s[wd];
      cnt += __popcll(m);
      if (m) last = wd * 64 + 63 - __clzll(m);
    }
    K_s = cnt;
  }
  __syncthreads();
  int K = K_s;

  // --- Phase 5: c0/c1 per t (coalesced writes) ---
#pragma unroll
  for (int it = 0; it < 2; it++) {
    int t = tid + it * 1024;
    if (t >= TLEN) continue;
    unsigned long long wd = mask_s[t >> 6];
    int bit = t & 63;
    unsigned long long below = wd & ((1ull << bit) - 1ull);
    int pf = below ? ((t & ~63) + 63 - __clzll(below)) : lastw_s[t >> 6];
    float Spf = (pf >= 0) ? S_s[pf] : 0.f;
    float accb = ((t > 0) ? S_s[t - 1] : 0.f) - Spf;
    bool fire = (wd >> bit) & 1ull;
    float c0 = fire ? (1.0f - accb) : w_s[t];
    float c1 = (S_s[t] - Spf) - 1.0f;
    c01G[b * TLEN + t] = float2{c0, c1};
  }

  // --- Phase 6: packed per-frame ranges AB[m] = {Af, Bl} ---
#pragma unroll
  for (int it = 0; it < 2; it++) {
    int m = tid + it * 1024;
    if (m >= MLEN) continue;
    int af = (m == 0) ? 0 : ((m <= K) ? (int)F_s[m - 1] : 0x7fffffff);
    int bl = (m < K) ? (int)F_s[m] : ((m == K) ? TLEN - 1 : -1);
    AB[(size_t)b * MLEN + m] = int2{af, bl};
  }
}

// K3: one block per (b, 16-frame chunk); 128 threads x float4 covers D=512.
// Frames in a chunk cover a contiguous t-range; boundary rows shared by
// consecutive frames are re-read from L1, not L2/HBM. Within [a, e]:
// only t==a (for m>0) takes the leftover c1; all else c0.
__global__ __launch_bounds__(128) void gather_kernel(
    const float* __restrict__ feat, const float2* __restrict__ c01G,
    const int2* __restrict__ AB, float* __restrict__ out) {
  int blk = blockIdx.x;
  int b = blk / CPB, chunk = blk % CPB;
  int m0 = chunk * FPB;
  int m1 = min(m0 + FPB, MLEN);
  const float4* f4 = (const float4*)feat + (size_t)b * TLEN * (DIM / 4);
  const float2* crow = c01G + b * TLEN;
  const int2* abrow = AB + (size_t)b * MLEN;
  float4* orow = (float4*)out + ((size_t)b * MLEN + m0) * (DIM / 4) + threadIdx.x;
  for (int m = m0; m < m1; m++, orow += DIM / 4) {
    int2 ab = abrow[m];
    int a = ab.x, e = ab.y;
    int afire = (m > 0) ? a : -1;           // t that contributes c1
    float4 acc = {0.f, 0.f, 0.f, 0.f};
    for (int t = a; t <= e; t++) {          // empty when frame untouched
      float2 c01 = crow[t];
      float c = (t == afire) ? c01.y : c01.x;
      float4 f = f4[(size_t)t * (DIM / 4) + threadIdx.x];
      acc.x += c * f.x; acc.y += c * f.y; acc.z += c * f.z; acc.w += c * f.w;
    }
    *orow = acc;
  }
}

extern "C" void kernel_launch(void* const* d_in, const int* in_sizes, int n_in,
                              void* d_out, int out_size, void* d_ws, size_t ws_size,
                              hipStream_t stream) {
  const float* feat = (const float*)d_in[0];
  // d_in[1] = hlens (unused by the reference computation)
  const float* W    = (const float*)d_in[2];
  const float* bias = (const float*)d_in[3];

  float* out       = (float*)d_out;
  float* feat_new  = out;                                  // B*M*D floats
  float* hlens_out = out + (size_t)BATCH * MLEN * DIM;     // 8 floats (int values)

  char* ws = (char*)d_ws;
  float*  weight = (float*)ws;                             // B*T floats   (64000 B)
  float2* c01    = (float2*)(ws + 64000);                  // B*T float2  (128000 B)
  int2*   AB     = (int2*)(ws + 192000);                   // B*M int2    (128064 B)

  weight_kernel<<<(BATCH * TLEN) / 4, 256, 0, stream>>>(feat, W, bias, weight);
  scan_kernel<<<BATCH, NTH, 0, stream>>>(weight, hlens_out, c01, AB);
  gather_kernel<<<BATCH * CPB, 128, 0, stream>>>(feat, c01, AB, feat_new);
}

// Round 7
// 102.477 us; speedup vs baseline: 1.1003x; 1.1003x over previous
//
#include <hip/hip_runtime.h>
#include <math.h>

#define BATCH 8
#define TLEN 2000
#define DIM 512
#define MLEN (TLEN + 1)
#define NTH 1024             // scan block size
#define NWORD 32             // fire bitmask words (2000 bits)
#define MAXLVL 11

// K1: weight[b,t] = sigmoid(dot(feat[b,t,:], W) + bias). One wave per row.
__global__ __launch_bounds__(256) void weight_kernel(
    const float* __restrict__ feat, const float* __restrict__ W,
    const float* __restrict__ bias, float* __restrict__ weight) {
  int gwave = (blockIdx.x * 256 + threadIdx.x) >> 6;   // global wave id = row
  int lane  = threadIdx.x & 63;
  if (gwave >= BATCH * TLEN) return;
  const float4* f4 = (const float4*)feat + (size_t)gwave * (DIM / 4) + lane * 2;
  const float4* w4 = (const float4*)W + lane * 2;
  float4 a0 = f4[0], a1 = f4[1];
  float4 b0 = w4[0], b1 = w4[1];
  float s = a0.x * b0.x + a0.y * b0.y + a0.z * b0.z + a0.w * b0.w +
            a1.x * b1.x + a1.y * b1.y + a1.z * b1.z + a1.w * b1.w;
#pragma unroll
  for (int off = 32; off > 0; off >>= 1) s += __shfl_xor(s, off, 64);
  if (lane == 0) {
    float x = s + bias[0];
    weight[gwave] = 1.0f / (1.0f + expf(-x));
  }
}

// K2: fully parallel integrate-and-fire. Prefix sum (wave shuffles) ->
// next-fire table G0 (batched binary search) -> orbit via binary lifting
// with fused F-extension and early exit -> fire bitmask -> c0/c1 and
// packed per-frame ranges AB.
__global__ __launch_bounds__(NTH) void scan_kernel(
    const float* __restrict__ weight, float* __restrict__ hlens_out,
    float2* __restrict__ c01G, int2* __restrict__ AB) {
  int b = blockIdx.x;
  int tid = threadIdx.x;
  int lane = tid & 63, wid = tid >> 6;

  __shared__ float w_s[TLEN];
  __shared__ float S_s[TLEN];
  __shared__ float wtot[16];
  __shared__ unsigned short Ga_s[MLEN];    // ping
  __shared__ unsigned short Gb_s[MLEN];    // pong
  __shared__ unsigned short F_s[2048];     // fire positions (K <= 1000)
  __shared__ unsigned long long mask_s[NWORD];
  __shared__ int lastw_s[NWORD];           // last fire index < 64*w (or -1)
  __shared__ int done_lv[MAXLVL];
  __shared__ int K_s;

  // --- Phase 1: load + prefix sum via wave shuffles (2 elems/thread) ---
  const float* wrow = weight + b * TLEN;
  int base = tid * 2;
  float w0 = 0.f, w1 = 0.f;
  if (base < TLEN) {
    float2 v = *(const float2*)(wrow + base);
    w0 = v.x; w1 = v.y;
  }
  float mysum = w0 + w1;
  float sc = mysum;
#pragma unroll
  for (int d = 1; d < 64; d <<= 1) {
    float o = __shfl_up(sc, d, 64);
    if (lane >= d) sc += o;
  }
  if (lane == 63) wtot[wid] = sc;
  if (tid < NWORD) mask_s[tid] = 0ull;
  if (tid < MAXLVL) done_lv[tid] = 1;
  __syncthreads();
  float woff = 0.f;
  for (int j = 0; j < wid; j++) woff += wtot[j];
  float excl = woff + (sc - mysum);
  if (base < TLEN) {
    w_s[base] = w0; w_s[base + 1] = w1;
    S_s[base] = excl + w0;
    S_s[base + 1] = excl + w0 + w1;
  }
  if (tid == 0) {
    float tot = 0.f;
    for (int j = 0; j < 16; j++) tot += wtot[j];
    hlens_out[b] = ceilf(tot);              // hlens tol ~20: order irrelevant
  }
  __syncthreads();

  // --- Phase 2: G0[s] = min t>s with S[t] > S[s]+1; t0 = min t, S[t] > 1 ---
  {
    int l0 = tid + 1, r0 = TLEN;  float tg0 = S_s[tid] + 1.0f;
    int s1v = tid + 1024;
    bool has1 = (s1v < TLEN);
    int l1 = has1 ? s1v + 1 : TLEN, r1 = TLEN;
    float tg1 = has1 ? S_s[s1v] + 1.0f : 0.f;
    bool has2 = (tid == 0);
    int l2 = 0, r2 = has2 ? TLEN : 0;
#pragma unroll
    for (int step = 0; step < MAXLVL; step++) {
      if (l0 < r0) { int m = (l0 + r0) >> 1; if (S_s[m] > tg0) r0 = m; else l0 = m + 1; }
      if (l1 < r1) { int m = (l1 + r1) >> 1; if (S_s[m] > tg1) r1 = m; else l1 = m + 1; }
      if (l2 < r2) { int m = (l2 + r2) >> 1; if (S_s[m] > 1.0f) r2 = m; else l2 = m + 1; }
    }
    Ga_s[tid] = (unsigned short)l0;
    if (has1) Ga_s[s1v] = (unsigned short)l1;
    F_s[tid] = (unsigned short)TLEN;
    F_s[tid + 1024] = (unsigned short)TLEN;
    if (tid == 0) {
      Ga_s[TLEN] = (unsigned short)TLEN;    // sentinel self-loop
      F_s[0] = (unsigned short)l2;          // first fire (TLEN if none)
    }
  }
  __syncthreads();

  // --- Phase 3: lifting + fused orbit doubling, 1 barrier/level ---
  {
    unsigned short* cur = Ga_s;
    unsigned short* nxt = Gb_s;
    int flen = 1;
    for (int lvl = 0; lvl < MAXLVL; lvl++) {
      int s0 = tid, s1v = tid + 1024;
      int g20 = (int)cur[cur[s0]];
      int g21 = (s1v <= TLEN) ? (int)cur[cur[s1v]] : TLEN;
      int i0 = tid, i1 = tid + 1024;
      int nv0 = -1, nv1 = -1;
      if (i0 < flen) nv0 = (int)cur[F_s[i0]];
      if (i1 < flen) nv1 = (int)cur[F_s[i1]];
      nxt[s0] = (unsigned short)g20;
      if (s1v <= TLEN) nxt[s1v] = (unsigned short)g21;
      if (i0 < flen) { F_s[flen + i0] = (unsigned short)nv0; if (nv0 < TLEN) done_lv[lvl] = 0; }
      if (i1 < flen) { F_s[flen + i1] = (unsigned short)nv1; if (nv1 < TLEN) done_lv[lvl] = 0; }
      __syncthreads();
      flen <<= 1;
      unsigned short* t = cur; cur = nxt; nxt = t;
      if (done_lv[lvl]) break;
    }
  }

  // --- Phase 4: fire bitmask scatter ---
  {
    int t0v = (int)F_s[tid];
    int t1v = (int)F_s[tid + 1024];
    if (t0v < TLEN) atomicOr(&mask_s[t0v >> 6], 1ull << (t0v & 63));
    if (t1v < TLEN) atomicOr(&mask_s[t1v >> 6], 1ull << (t1v & 63));
  }
  __syncthreads();
  if (tid == 0) {
    int last = -1, cnt = 0;
    for (int wd = 0; wd < NWORD; wd++) {
      lastw_s[wd] = last;
      unsigned long long m = mask_s[wd];
      cnt += __popcll(m);
      if (m) last = wd * 64 + 63 - __clzll(m);
    }
    K_s = cnt;
  }
  __syncthreads();
  int K = K_s;

  // --- Phase 5: c0/c1 per t (coalesced writes) ---
#pragma unroll
  for (int it = 0; it < 2; it++) {
    int t = tid + it * 1024;
    if (t >= TLEN) continue;
    unsigned long long wd = mask_s[t >> 6];
    int bit = t & 63;
    unsigned long long below = wd & ((1ull << bit) - 1ull);
    int pf = below ? ((t & ~63) + 63 - __clzll(below)) : lastw_s[t >> 6];
    float Spf = (pf >= 0) ? S_s[pf] : 0.f;
    float accb = ((t > 0) ? S_s[t - 1] : 0.f) - Spf;
    bool fire = (wd >> bit) & 1ull;
    float c0 = fire ? (1.0f - accb) : w_s[t];
    float c1 = (S_s[t] - Spf) - 1.0f;
    c01G[b * TLEN + t] = float2{c0, c1};
  }

  // --- Phase 6: packed per-frame ranges AB[m] = {Af, Bl} ---
#pragma unroll
  for (int it = 0; it < 2; it++) {
    int m = tid + it * 1024;
    if (m >= MLEN) continue;
    int af = (m == 0) ? 0 : ((m <= K) ? (int)F_s[m - 1] : 0x7fffffff);
    int bl = (m < K) ? (int)F_s[m] : ((m == K) ? TLEN - 1 : -1);
    AB[(size_t)b * MLEN + m] = int2{af, bl};
  }
}

// K3: one WAVE per (b, m) frame; 4 waves (256 threads) per block. Each lane
// covers 8 floats of D=512 (two float4s, 64 lanes x 32 B = one 2 KB row).
// Fully independent waves: same 16016 latency chains as the 1-frame-per-block
// version, 4x fewer blocks, no __syncthreads.
__global__ __launch_bounds__(256) void gather_kernel(
    const float* __restrict__ feat, const float2* __restrict__ c01G,
    const int2* __restrict__ AB, float* __restrict__ out) {
  int bm = (blockIdx.x * 256 + threadIdx.x) >> 6;       // global wave id = frame
  int lane = threadIdx.x & 63;
  if (bm >= BATCH * MLEN) return;
  int b = bm / MLEN, m = bm % MLEN;
  int2 ab = AB[(size_t)bm];
  int a = ab.x, e = ab.y;
  int afire = (m > 0) ? a : -1;             // t that contributes c1
  float4 acc0 = {0.f, 0.f, 0.f, 0.f};
  float4 acc1 = {0.f, 0.f, 0.f, 0.f};
  const float4* f4 = (const float4*)feat + (size_t)b * TLEN * (DIM / 4) + lane * 2;
  const float2* crow = c01G + b * TLEN;
  for (int t = a; t <= e; t++) {            // empty when frame untouched
    float2 c01 = crow[t];
    float c = (t == afire) ? c01.y : c01.x;
    const float4* fr = f4 + (size_t)t * (DIM / 4);
    float4 fa = fr[0], fb = fr[1];
    acc0.x += c * fa.x; acc0.y += c * fa.y; acc0.z += c * fa.z; acc0.w += c * fa.w;
    acc1.x += c * fb.x; acc1.y += c * fb.y; acc1.z += c * fb.z; acc1.w += c * fb.w;
  }
  float4* orow = (float4*)out + (size_t)bm * (DIM / 4) + lane * 2;
  orow[0] = acc0;
  orow[1] = acc1;
}

extern "C" void kernel_launch(void* const* d_in, const int* in_sizes, int n_in,
                              void* d_out, int out_size, void* d_ws, size_t ws_size,
                              hipStream_t stream) {
  const float* feat = (const float*)d_in[0];
  // d_in[1] = hlens (unused by the reference computation)
  const float* W    = (const float*)d_in[2];
  const float* bias = (const float*)d_in[3];

  float* out       = (float*)d_out;
  float* feat_new  = out;                                  // B*M*D floats
  float* hlens_out = out + (size_t)BATCH * MLEN * DIM;     // 8 floats (int values)

  char* ws = (char*)d_ws;
  float*  weight = (float*)ws;                             // B*T floats   (64000 B)
  float2* c01    = (float2*)(ws + 64000);                  // B*T float2  (128000 B)
  int2*   AB     = (int2*)(ws + 192000);                   // B*M int2    (128064 B)

  weight_kernel<<<(BATCH * TLEN) / 4, 256, 0, stream>>>(feat, W, bias, weight);
  scan_kernel<<<BATCH, NTH, 0, stream>>>(weight, hlens_out, c01, AB);
  int nframes = BATCH * MLEN;                              // one wave each
  gather_kernel<<<(nframes + 3) / 4, 256, 0, stream>>>(feat, c01, AB, feat_new);
}

// Round 8
// 100.484 us; speedup vs baseline: 1.1221x; 1.0198x over previous
//
#include <hip/hip_runtime.h>
#include <math.h>

#define BATCH 8
#define TLEN 2000
#define DIM 512
#define MLEN (TLEN + 1)
#define NTH 1024             // scan block size
#define MAXLVL 11

// K1: weight[b,t] = sigmoid(dot(feat[b,t,:], W) + bias). One wave per row.
__global__ __launch_bounds__(256) void weight_kernel(
    const float* __restrict__ feat, const float* __restrict__ W,
    const float* __restrict__ bias, float* __restrict__ weight) {
  int gwave = (blockIdx.x * 256 + threadIdx.x) >> 6;   // global wave id = row
  int lane  = threadIdx.x & 63;
  if (gwave >= BATCH * TLEN) return;
  const float4* f4 = (const float4*)feat + (size_t)gwave * (DIM / 4) + lane * 2;
  const float4* w4 = (const float4*)W + lane * 2;
  float4 a0 = f4[0], a1 = f4[1];
  float4 b0 = w4[0], b1 = w4[1];
  float s = a0.x * b0.x + a0.y * b0.y + a0.z * b0.z + a0.w * b0.w +
            a1.x * b1.x + a1.y * b1.y + a1.z * b1.z + a1.w * b1.w;
#pragma unroll
  for (int off = 32; off > 0; off >>= 1) s += __shfl_xor(s, off, 64);
  if (lane == 0) {
    float x = s + bias[0];
    weight[gwave] = 1.0f / (1.0f + expf(-x));
  }
}

// K2: fully parallel integrate-and-fire. Prefix sum (wave shuffles) ->
// next-fire table G0 (batched binary search) -> orbit via binary lifting
// with fused F-extension and early exit -> per-frame descriptors
// {a, e, cL, cR}. No c01 array, no fire bitmask.
__global__ __launch_bounds__(NTH) void scan_kernel(
    const float* __restrict__ weight, float* __restrict__ hlens_out,
    int4* __restrict__ AB) {
  int b = blockIdx.x;
  int tid = threadIdx.x;
  int lane = tid & 63, wid = tid >> 6;

  __shared__ float w_s[TLEN];
  __shared__ float S_s[TLEN];
  __shared__ float wtot[16];
  __shared__ unsigned short Ga_s[MLEN];    // ping
  __shared__ unsigned short Gb_s[MLEN];    // pong
  __shared__ unsigned short F_s[2048];     // fire positions (K <= 1000)
  __shared__ int done_lv[MAXLVL];
  __shared__ int K_s;

  // --- Phase 1: load + prefix sum via wave shuffles (2 elems/thread) ---
  const float* wrow = weight + b * TLEN;
  int base = tid * 2;
  float w0 = 0.f, w1 = 0.f;
  if (base < TLEN) {
    float2 v = *(const float2*)(wrow + base);
    w0 = v.x; w1 = v.y;
  }
  float mysum = w0 + w1;
  float sc = mysum;
#pragma unroll
  for (int d = 1; d < 64; d <<= 1) {
    float o = __shfl_up(sc, d, 64);
    if (lane >= d) sc += o;
  }
  if (lane == 63) wtot[wid] = sc;
  if (tid < MAXLVL) done_lv[tid] = 1;
  __syncthreads();
  float woff = 0.f;
  for (int j = 0; j < wid; j++) woff += wtot[j];
  float excl = woff + (sc - mysum);
  if (base < TLEN) {
    w_s[base] = w0; w_s[base + 1] = w1;
    S_s[base] = excl + w0;
    S_s[base + 1] = excl + w0 + w1;
  }
  if (tid == 0) {
    float tot = 0.f;
    for (int j = 0; j < 16; j++) tot += wtot[j];
    hlens_out[b] = ceilf(tot);              // hlens tol ~20: order irrelevant
  }
  __syncthreads();

  // --- Phase 2: G0[s] = min t>s with S[t] > S[s]+1; t0 = min t, S[t] > 1 ---
  {
    int l0 = tid + 1, r0 = TLEN;  float tg0 = S_s[tid] + 1.0f;
    int s1v = tid + 1024;
    bool has1 = (s1v < TLEN);
    int l1 = has1 ? s1v + 1 : TLEN, r1 = TLEN;
    float tg1 = has1 ? S_s[s1v] + 1.0f : 0.f;
    bool has2 = (tid == 0);
    int l2 = 0, r2 = has2 ? TLEN : 0;
#pragma unroll
    for (int step = 0; step < MAXLVL; step++) {
      if (l0 < r0) { int m = (l0 + r0) >> 1; if (S_s[m] > tg0) r0 = m; else l0 = m + 1; }
      if (l1 < r1) { int m = (l1 + r1) >> 1; if (S_s[m] > tg1) r1 = m; else l1 = m + 1; }
      if (l2 < r2) { int m = (l2 + r2) >> 1; if (S_s[m] > 1.0f) r2 = m; else l2 = m + 1; }
    }
    Ga_s[tid] = (unsigned short)l0;
    if (has1) Ga_s[s1v] = (unsigned short)l1;
    F_s[tid] = (unsigned short)TLEN;
    F_s[tid + 1024] = (unsigned short)TLEN;
    if (tid == 0) {
      Ga_s[TLEN] = (unsigned short)TLEN;    // sentinel self-loop
      F_s[0] = (unsigned short)l2;          // first fire (TLEN if none)
    }
  }
  __syncthreads();

  // --- Phase 3: lifting + fused orbit doubling, 1 barrier/level ---
  {
    unsigned short* cur = Ga_s;
    unsigned short* nxt = Gb_s;
    int flen = 1;
    for (int lvl = 0; lvl < MAXLVL; lvl++) {
      int s0 = tid, s1v = tid + 1024;
      int g20 = (int)cur[cur[s0]];
      int g21 = (s1v <= TLEN) ? (int)cur[cur[s1v]] : TLEN;
      int i0 = tid, i1 = tid + 1024;
      int nv0 = -1, nv1 = -1;
      if (i0 < flen) nv0 = (int)cur[F_s[i0]];
      if (i1 < flen) nv1 = (int)cur[F_s[i1]];
      nxt[s0] = (unsigned short)g20;
      if (s1v <= TLEN) nxt[s1v] = (unsigned short)g21;
      if (i0 < flen) { F_s[flen + i0] = (unsigned short)nv0; if (nv0 < TLEN) done_lv[lvl] = 0; }
      if (i1 < flen) { F_s[flen + i1] = (unsigned short)nv1; if (nv1 < TLEN) done_lv[lvl] = 0; }
      __syncthreads();
      flen <<= 1;
      unsigned short* t = cur; cur = nxt; nxt = t;
      if (done_lv[lvl]) break;
    }
  }

  // --- Phase 4: K = number of fires (unique k with F[k]==T, F[k-1]<T) ---
#pragma unroll
  for (int it = 0; it < 2; it++) {
    int k = tid + it * 1024;
    if ((int)F_s[k] == TLEN && (k == 0 || (int)F_s[k - 1] < TLEN)) K_s = k;
  }
  __syncthreads();
  int K = K_s;

  // --- Phase 5: per-frame descriptors AB[m] = {a, e, cL, cR} ---
  // Interior t of a frame uses w[t]; t==a (m>0) uses cL; t==e uses cR
  // (for m==K we store cR=w[T-1] so the same rule applies; cL wins at a==e).
#pragma unroll
  for (int it = 0; it < 2; it++) {
    int m = tid + it * 1024;
    if (m >= MLEN) continue;
    int a, e;
    float cL = 0.f, cR = 0.f;
    if (m == 0) {
      a = 0;
      if (K > 0) {
        e = (int)F_s[0];
        cR = 1.0f - ((e > 0) ? S_s[e - 1] : 0.f);  // fire split, acc base 0
      } else {
        e = TLEN - 1;
        cR = w_s[TLEN - 1];                        // no fire: plain weight
      }
    } else if (m <= K) {
      int f1 = (int)F_s[m - 1];
      float Sp0 = (m >= 2) ? S_s[(int)F_s[m - 2]] : 0.f;
      a = f1;
      cL = S_s[f1] - Sp0 - 1.0f;                   // leftover c1 at t=a
      if (m < K) {
        e = (int)F_s[m];
        cR = 1.0f - (S_s[e - 1] - S_s[f1]);        // fire split c0 at t=e
      } else {
        e = TLEN - 1;
        cR = w_s[TLEN - 1];                        // trailing partial frame
      }
    } else {
      a = 0x7fffffff; e = -1;                      // empty frame
    }
    int4 pk;
    pk.x = a; pk.y = e;
    pk.z = __float_as_int(cL);
    pk.w = __float_as_int(cR);
    AB[(size_t)b * MLEN + m] = pk;
  }
}

// K3: one WAVE per (b, m) frame; 4 waves (256 threads) per block. Each lane
// covers 8 floats of D=512 (two float4s). Coefficients: t==a (m>0) -> cL,
// t==e -> cR, else w[t] (8 KB/batch row, L1/L2-hot broadcast loads).
__global__ __launch_bounds__(256) void gather_kernel(
    const float* __restrict__ feat, const float* __restrict__ weight,
    const int4* __restrict__ AB, float* __restrict__ out) {
  int bm = (blockIdx.x * 256 + threadIdx.x) >> 6;       // global wave id = frame
  int lane = threadIdx.x & 63;
  if (bm >= BATCH * MLEN) return;
  int b = bm / MLEN, m = bm % MLEN;
  int4 ab = AB[(size_t)bm];
  int a = ab.x, e = ab.y;
  float cL = __int_as_float(ab.z), cR = __int_as_float(ab.w);
  float4 acc0 = {0.f, 0.f, 0.f, 0.f};
  float4 acc1 = {0.f, 0.f, 0.f, 0.f};
  const float4* f4 = (const float4*)feat + (size_t)b * TLEN * (DIM / 4) + lane * 2;
  const float* wrow = weight + b * TLEN;
  for (int t = a; t <= e; t++) {            // empty when frame untouched
    float c = (t == a && m > 0) ? cL : ((t == e) ? cR : wrow[t]);
    const float4* fr = f4 + (size_t)t * (DIM / 4);
    float4 fa = fr[0], fb = fr[1];
    acc0.x += c * fa.x; acc0.y += c * fa.y; acc0.z += c * fa.z; acc0.w += c * fa.w;
    acc1.x += c * fb.x; acc1.y += c * fb.y; acc1.z += c * fb.z; acc1.w += c * fb.w;
  }
  float4* orow = (float4*)out + (size_t)bm * (DIM / 4) + lane * 2;
  orow[0] = acc0;
  orow[1] = acc1;
}

extern "C" void kernel_launch(void* const* d_in, const int* in_sizes, int n_in,
                              void* d_out, int out_size, void* d_ws, size_t ws_size,
                              hipStream_t stream) {
  const float* feat = (const float*)d_in[0];
  // d_in[1] = hlens (unused by the reference computation)
  const float* W    = (const float*)d_in[2];
  const float* bias = (const float*)d_in[3];

  float* out       = (float*)d_out;
  float* feat_new  = out;                                  // B*M*D floats
  float* hlens_out = out + (size_t)BATCH * MLEN * DIM;     // 8 floats (int values)

  char* ws = (char*)d_ws;
  float* weight = (float*)ws;                              // B*T floats   (64000 B)
  int4*  AB     = (int4*)(ws + 64000);                     // B*M int4    (256128 B)

  weight_kernel<<<(BATCH * TLEN) / 4, 256, 0, stream>>>(feat, W, bias, weight);
  scan_kernel<<<BATCH, NTH, 0, stream>>>(weight, hlens_out, AB);
  int nframes = BATCH * MLEN;                              // one wave each
  gather_kernel<<<(nframes + 3) / 4, 256, 0, stream>>>(feat, weight, AB, feat_new);
}